// Round 3
// 140.643 us; speedup vs baseline: 1.0434x; 1.0434x over previous
//
#include <hip/hip_runtime.h>
#include <cstdint>
#include <cstddef>

#define D 64

typedef float    f32x4 __attribute__((ext_vector_type(4)));
typedef short    s16x8 __attribute__((ext_vector_type(8)));
typedef uint32_t u32x4 __attribute__((ext_vector_type(4)));

// round-to-nearest-even fp32 -> bf16 (bits in low 16)
__device__ __forceinline__ uint32_t rne_bf16(float f) {
    uint32_t x = __float_as_uint(f);
    return (x + 0x7fffu + ((x >> 16) & 1u)) >> 16;
}
__device__ __forceinline__ float bf16lo(uint32_t u) { return __uint_as_float(u << 16); }
__device__ __forceinline__ float bf16hi(uint32_t u) { return __uint_as_float(u & 0xffff0000u); }

// Kernel 1: XWh[node] = bf16( X @ W )  via mfma_f32_16x16x32_bf16.
// Exploits linearity: sum_j X[j] @ W == sum_j (X@W)[j], so the dense GEMM is
// hoisted BEFORE the aggregation. Traffic identical to the old cast kernel
// (read 25.6MB fp32, write 12.8MB bf16); MFMA rides along for free.
//
// Frag roles swapped vs usual: A = W^T (m=feature), B = X rows (n=node), so
// D[m=feature][n=node]. C/D: col=lane&15 -> node, row=q*4+reg -> feature.
// Each lane then holds 4 CONSECUTIVE features of one node -> in-lane bf16
// pack, 8B coalesced store, no cross-lane traffic.
__global__ __launch_bounds__(256) void xw_gemm_kernel(
    const float* __restrict__ X, const float* __restrict__ W,
    uint32_t* __restrict__ XWh, int n_nodes)
{
    const int lane = threadIdx.x & 63;
    const int n = lane & 15;
    const int q = lane >> 4;

    // A-frag (W^T): A[m = c*16 + n][k = kb*32 + q*8 + j] = W[k*64 + c*16 + n]
    s16x8 Af[4][2];
#pragma unroll
    for (int c = 0; c < 4; ++c)
#pragma unroll
        for (int kb = 0; kb < 2; ++kb) {
            s16x8 af;
#pragma unroll
            for (int j = 0; j < 8; ++j) {
                const int k = kb * 32 + q * 8 + j;
                af[j] = (short)rne_bf16(W[k * D + c * 16 + n]);
            }
            Af[c][kb] = af;
        }

    const int n_tiles = (n_nodes + 15) / 16;
    const int gwave = (int)((blockIdx.x * blockDim.x + threadIdx.x) >> 6);
    const int nwaves = (int)((gridDim.x * blockDim.x) >> 6);

    for (int t = gwave; t < n_tiles; t += nwaves) {
        const int m0 = t * 16;
        int arow = m0 + n;
        if (arow >= n_nodes) arow = n_nodes - 1;  // clamp (tail tile)
        const float* xp = X + (size_t)arow * D;

        // B-frag: B[k = kb*32 + q*8 + j][n] = X[node n][k] -- 8 consecutive f32
        s16x8 Bf[2];
#pragma unroll
        for (int kb = 0; kb < 2; ++kb) {
            const f32x4 x0 = __builtin_nontemporal_load((const f32x4*)(xp + kb * 32 + q * 8));
            const f32x4 x1 = __builtin_nontemporal_load((const f32x4*)(xp + kb * 32 + q * 8 + 4));
            s16x8 b;
            b[0] = (short)rne_bf16(x0.x); b[1] = (short)rne_bf16(x0.y);
            b[2] = (short)rne_bf16(x0.z); b[3] = (short)rne_bf16(x0.w);
            b[4] = (short)rne_bf16(x1.x); b[5] = (short)rne_bf16(x1.y);
            b[6] = (short)rne_bf16(x1.z); b[7] = (short)rne_bf16(x1.w);
            Bf[kb] = b;
        }

        const bool live = (m0 + n) < n_nodes;
#pragma unroll
        for (int c = 0; c < 4; ++c) {
            f32x4 z = {0.f, 0.f, 0.f, 0.f};
            z = __builtin_amdgcn_mfma_f32_16x16x32_bf16(Af[c][0], Bf[0], z, 0, 0, 0);
            z = __builtin_amdgcn_mfma_f32_16x16x32_bf16(Af[c][1], Bf[1], z, 0, 0, 0);
            if (live) {
                // lane holds features c*16 + q*4 + {0..3} of node m0+n
                uint2 o;
                o.x = rne_bf16(z[0]) | (rne_bf16(z[1]) << 16);
                o.y = rne_bf16(z[2]) | (rne_bf16(z[3]) << 16);
                *(uint2*)(XWh + (size_t)(m0 + n) * 32 + c * 8 + q * 2) = o;
            }
        }
    }
}

// Kernel 2: out[r] = fp32( sum_{e in row r} XWh[ci[e]] ).
// ONE row per wave. o = lane>>3 (edge slot 0..7), p = lane&7 (feature octet,
// u32x4 = 8 bf16 = full 128B row across 8 lanes). 8 edges per load instr.
// Main iter = 32 edges: 4 independent idx loads then 4 independent gathers
// -> up to 8 loads in flight per wave. Hot loop identical to the proven
// gather3; only the epilogue changed (fp32 out, no bf16 re-pack).
__global__ __launch_bounds__(256) void gather_out_kernel(
    const uint32_t* __restrict__ XWh, const int* __restrict__ rp,
    const int* __restrict__ ci, float* __restrict__ out, int n_nodes)
{
    const int lane = threadIdx.x & 63;
    const int o = lane >> 3;
    const int p = lane & 7;
    const int row = (int)((blockIdx.x * blockDim.x + threadIdx.x) >> 6);
    if (row >= n_nodes) return;

    const int e0 = rp[row];
    const int e1 = rp[row + 1];

    float a[8] = {0,0,0,0,0,0,0,0};
    float b[8] = {0,0,0,0,0,0,0,0};

    int e = e0;
    // main: 32 edges per iteration, all loads independent
    for (; e + 32 <= e1; e += 32) {
        const int i0 = ci[e      + o];
        const int i1 = ci[e +  8 + o];
        const int i2 = ci[e + 16 + o];
        const int i3 = ci[e + 24 + o];
        const u32x4 u0 = *(const u32x4*)(XWh + (size_t)i0 * 32 + p * 4);
        const u32x4 u1 = *(const u32x4*)(XWh + (size_t)i1 * 32 + p * 4);
        const u32x4 u2 = *(const u32x4*)(XWh + (size_t)i2 * 32 + p * 4);
        const u32x4 u3 = *(const u32x4*)(XWh + (size_t)i3 * 32 + p * 4);
#pragma unroll
        for (int k = 0; k < 4; ++k) {
            a[2*k] += bf16lo(u0[k]); a[2*k+1] += bf16hi(u0[k]);
            b[2*k] += bf16lo(u1[k]); b[2*k+1] += bf16hi(u1[k]);
            a[2*k] += bf16lo(u2[k]); a[2*k+1] += bf16hi(u2[k]);
            b[2*k] += bf16lo(u3[k]); b[2*k+1] += bf16hi(u3[k]);
        }
    }
    // 16-edge step
    if (e + 16 <= e1) {
        const int i0 = ci[e     + o];
        const int i1 = ci[e + 8 + o];
        const u32x4 u0 = *(const u32x4*)(XWh + (size_t)i0 * 32 + p * 4);
        const u32x4 u1 = *(const u32x4*)(XWh + (size_t)i1 * 32 + p * 4);
#pragma unroll
        for (int k = 0; k < 4; ++k) {
            a[2*k] += bf16lo(u0[k]); a[2*k+1] += bf16hi(u0[k]);
            b[2*k] += bf16lo(u1[k]); b[2*k+1] += bf16hi(u1[k]);
        }
        e += 16;
    }
    // 8-edge step
    if (e + 8 <= e1) {
        const int i0 = ci[e + o];
        const u32x4 u0 = *(const u32x4*)(XWh + (size_t)i0 * 32 + p * 4);
#pragma unroll
        for (int k = 0; k < 4; ++k) {
            a[2*k] += bf16lo(u0[k]); a[2*k+1] += bf16hi(u0[k]);
        }
        e += 8;
    }
    // final 0..7 edges, predicated over o
    if (o < e1 - e) {
        const int i0 = ci[e + o];
        const u32x4 u0 = *(const u32x4*)(XWh + (size_t)i0 * 32 + p * 4);
#pragma unroll
        for (int k = 0; k < 4; ++k) {
            b[2*k] += bf16lo(u0[k]); b[2*k+1] += bf16hi(u0[k]);
        }
    }

    // reduce across the 8 edge slots (bits 3..5 of lane); lanes 0..7 get sums
#pragma unroll
    for (int j = 0; j < 8; ++j) {
        float v = a[j] + b[j];
        v += __shfl_xor(v, 8, 64);
        v += __shfl_xor(v, 16, 64);
        v += __shfl_xor(v, 32, 64);
        a[j] = v;
    }
    if (lane < 8) {
        // lane p holds features p*8 .. p*8+7 of this row, fp32
        f32x4 w0 = {a[0], a[1], a[2], a[3]};
        f32x4 w1 = {a[4], a[5], a[6], a[7]};
        *(f32x4*)(out + (size_t)row * D + p * 8)     = w0;
        *(f32x4*)(out + (size_t)row * D + p * 8 + 4) = w1;
    }
}

// Fallback if ws can't hold XWh: fused per-row aggregate + shfl GEMM.
__global__ __launch_bounds__(256) void fused_kernel(
    const float* __restrict__ X, const float* __restrict__ W,
    const int* __restrict__ rp, const int* __restrict__ ci,
    float* __restrict__ out, int n_nodes)
{
    __shared__ float Wl[D * D];
    for (int i = threadIdx.x; i < D * D; i += 256) Wl[i] = W[i];
    __syncthreads();

    const int lane = threadIdx.x & 63;
    const int gwave = (int)((blockIdx.x * blockDim.x + threadIdx.x) >> 6);
    const int nwaves = (int)((gridDim.x * blockDim.x) >> 6);

    for (int row = gwave; row < n_nodes; row += nwaves) {
        int e0 = rp[row];
        int e1 = rp[row + 1];
        float acc = 0.f;
        for (int e = e0; e < e1; ++e) acc += X[ci[e] * D + lane];
        float sum = 0.f;
#pragma unroll
        for (int d = 0; d < D; ++d) {
            float a = __shfl(acc, d, 64);
            sum += a * Wl[d * D + lane];
        }
        out[row * D + lane] = sum;
    }
}

extern "C" void kernel_launch(void* const* d_in, const int* in_sizes, int n_in,
                              void* d_out, int out_size, void* d_ws, size_t ws_size,
                              hipStream_t stream)
{
    const float* X  = (const float*)d_in[0];   // [n, 64]
    const float* W  = (const float*)d_in[1];   // [64, 64]
    const int*   rp = (const int*)d_in[2];     // [n+1]
    const int*   ci = (const int*)d_in[3];     // [n_edges]
    float* out = (float*)d_out;

    const int n_nodes = in_sizes[2] - 1;
    const size_t row_bytes = 32 * sizeof(uint32_t);       // 128 B bf16 row
    const size_t need = (size_t)n_nodes * row_bytes;      // XWh only

    if (ws_size >= need) {
        uint32_t* XWh = (uint32_t*)d_ws;

        // K1: XWh = bf16(X @ W). ~1.5 tiles/wave; W-frag setup amortized.
        xw_gemm_kernel<<<1024, 256, 0, stream>>>(X, W, XWh, n_nodes);

        // K2: gather-aggregate rows of XWh -> fp32 out. 1 row/wave.
        const int gather_blocks = (n_nodes + 3) / 4;  // 4 waves/block
        gather_out_kernel<<<gather_blocks, 256, 0, stream>>>(XWh, rp, ci, out, n_nodes);
    } else {
        fused_kernel<<<2048, 256, 0, stream>>>(X, W, rp, ci, out, n_nodes);
    }
}